// Round 2
// baseline (44.186 us; speedup 1.0000x reference)
//
#include <hip/hip_runtime.h>
#include <hip/hip_bf16.h>

// Problem constants
#define M_ROWS   1792                 // 7 * 256 softpool rows
#define KDIM     512
#define OUT_FEAT_SZ (M_ROWS*1024)     // 1835008
#define OUT_HAT_SZ  (M_ROWS*512)      // 917504

typedef __attribute__((ext_vector_type(8))) __bf16 bf16x8;
typedef __attribute__((ext_vector_type(4))) float  f32x4;

__device__ __forceinline__ unsigned short f2bf(float f) {
    union { float f; unsigned int u; } v; v.f = f;
    unsigned int r = v.u + 0x7fffu + ((v.u >> 16) & 1u);   // RNE
    return (unsigned short)(r >> 16);
}

// f32 -> bf16 weight conversion (262144 elems each; blockIdx.y picks tensor)
__global__ __launch_bounds__(256) void cvt_k(
    const float* __restrict__ a, const float* __restrict__ b,
    unsigned short* __restrict__ oa, unsigned short* __restrict__ ob)
{
    const float* s = blockIdx.y ? b : a;
    unsigned short* d = blockIdx.y ? ob : oa;
    int i = blockIdx.x * 256 + threadIdx.x;   // 65536 threads, 4 elems each
    float4 v = reinterpret_cast<const float4*>(s)[i];
    ushort4 o; o.x=f2bf(v.x); o.y=f2bf(v.y); o.z=f2bf(v.z); o.w=f2bf(v.w);
    reinterpret_cast<ushort4*>(d)[i] = o;
}

// Fully fused: softpool3d (4,2,2)/(2,2,2) of the block's 16 output rows ->
// LDS {bf16 A-tile, f32 residual}, then C = A @ W^T + bias (+ residual for
// side 0), row-softmax over N=512, write hat + scaled feature half.
// Block = 16 rows x N=512, 4 waves; wave w owns cols [w*128, w*128+128).
__global__ __launch_bounds__(256) void fused_k(
    const float* __restrict__ x, const float* __restrict__ y,
    const unsigned short* __restrict__ wv_bf, const unsigned short* __restrict__ wt_bf,
    const float* __restrict__ b_v, const float* __restrict__ b_t,
    const float* __restrict__ wvec, float* __restrict__ d_out)
{
    const int side = blockIdx.y;
    const float* in          = side ? y     : x;
    const unsigned short* B  = side ? wt_bf : wv_bf;
    const float* bias        = side ? b_t   : b_v;
    const int mbase = blockIdx.x * 16;
    const int bp = mbase >> 8;       // b' (constant within tile: 256 % 16 == 0)
    const int l0 = mbase & 255;      // l' base

    __shared__ unsigned short tA[16 * 520];  // bf16 softpool tile (A), padded
    __shared__ float resl[16 * 516];         // f32 softpool (residual) -> logits

    const int tid = threadIdx.x;

    // ---- softpool phase: thread tid owns d' pair (2*tid, 2*tid+1), all 16 rows
    const float* base0 = in + ((size_t)(2*bp) * 512 + 2*l0) * 1024 + 4*tid;
    for (int r = 0; r < 16; ++r) {
        const float* base = base0 + (size_t)(2*r) * 1024;
        float num0=0.f, den0=0.f, num1=0.f, den1=0.f;
        #pragma unroll
        for (int i = 0; i < 4; ++i) {
            #pragma unroll
            for (int j = 0; j < 2; ++j) {
                float4 v = *reinterpret_cast<const float4*>(base + ((size_t)(i*512 + j))*1024);
                float e0=__expf(v.x), e1=__expf(v.y), e2=__expf(v.z), e3=__expf(v.w);
                num0 += e0*v.x + e1*v.y;  den0 += e0 + e1;
                num1 += e2*v.z + e3*v.w;  den1 += e2 + e3;
            }
        }
        float s0 = num0/den0, s1 = num1/den1;
        *reinterpret_cast<float2*>(&resl[r*516 + 2*tid]) = make_float2(s0, s1);
        unsigned int pk = (unsigned int)f2bf(s0) | ((unsigned int)f2bf(s1) << 16);
        *reinterpret_cast<unsigned int*>(&tA[r*520 + 2*tid]) = pk;
    }
    __syncthreads();

    // ---- GEMM phase
    const int lane = tid & 63;
    const int wid  = tid >> 6;
    const int arow = lane & 15;
    const int kq   = lane >> 4;    // 0..3
    const int nb   = wid * 128;

    f32x4 acc[8];
    #pragma unroll
    for (int t = 0; t < 8; ++t) acc[t] = (f32x4){0.f, 0.f, 0.f, 0.f};

    #pragma unroll 2
    for (int ks = 0; ks < 16; ++ks) {
        int kk = ks*32 + kq*8;
        bf16x8 af = *reinterpret_cast<const bf16x8*>(&tA[arow*520 + kk]);
        #pragma unroll
        for (int t = 0; t < 8; ++t) {
            const unsigned short* bptr = B + (size_t)(nb + t*16 + arow) * KDIM + kk;
            bf16x8 bf = *reinterpret_cast<const bf16x8*>(bptr);
            acc[t] = __builtin_amdgcn_mfma_f32_16x16x32_bf16(af, bf, acc[t], 0, 0, 0);
        }
    }

    // ---- epilogue: logits = acc + bias (+ residual, side 0), in-place in resl
    #pragma unroll
    for (int t = 0; t < 8; ++t) {
        int n = nb + t*16 + arow;
        float bn = bias[n];
        #pragma unroll
        for (int i = 0; i < 4; ++i) {
            int row = kq*4 + i;    // C/D: col=lane&15, row=(lane>>4)*4+i
            float v = acc[t][i] + bn;
            if (side == 0) v += resl[row*516 + n];
            resl[row*516 + n] = v;
        }
    }
    __syncthreads();

    // ---- block softmax: wave wid handles rows wid*4 .. wid*4+3 (full 512 cols)
    float ew0 = __expf(wvec[0]), ew1 = __expf(wvec[1]);
    float wsc = (side ? ew1 : ew0) / (ew0 + ew1);
    float* feat = d_out;
    float* hat  = d_out + OUT_FEAT_SZ + (size_t)side * OUT_HAT_SZ;

    for (int r = 0; r < 4; ++r) {
        int row = wid*4 + r;
        int m = mbase + row;
        const float* lp = &resl[row*516 + lane*8];
        float4 v0 = *reinterpret_cast<const float4*>(lp);
        float4 v1 = *reinterpret_cast<const float4*>(lp + 4);
        float mx = fmaxf(fmaxf(fmaxf(v0.x,v0.y), fmaxf(v0.z,v0.w)),
                         fmaxf(fmaxf(v1.x,v1.y), fmaxf(v1.z,v1.w)));
        #pragma unroll
        for (int s = 32; s; s >>= 1) mx = fmaxf(mx, __shfl_xor(mx, s));
        float e0=__expf(v0.x-mx), e1=__expf(v0.y-mx), e2=__expf(v0.z-mx), e3=__expf(v0.w-mx);
        float e4=__expf(v1.x-mx), e5=__expf(v1.y-mx), e6=__expf(v1.z-mx), e7=__expf(v1.w-mx);
        float sum = ((e0+e1)+(e2+e3)) + ((e4+e5)+(e6+e7));
        #pragma unroll
        for (int s = 32; s; s >>= 1) sum += __shfl_xor(sum, s);
        float inv = 1.f / sum;
        float4 p0 = {e0*inv, e1*inv, e2*inv, e3*inv};
        float4 p1 = {e4*inv, e5*inv, e6*inv, e7*inv};
        *reinterpret_cast<float4*>(&hat[(size_t)m*512 + lane*8])     = p0;
        *reinterpret_cast<float4*>(&hat[(size_t)m*512 + lane*8 + 4]) = p1;
        float4 f0 = {p0.x*wsc, p0.y*wsc, p0.z*wsc, p0.w*wsc};
        float4 f1 = {p1.x*wsc, p1.y*wsc, p1.z*wsc, p1.w*wsc};
        size_t fo = (size_t)m*1024 + side*512 + lane*8;
        *reinterpret_cast<float4*>(&feat[fo])     = f0;
        *reinterpret_cast<float4*>(&feat[fo + 4]) = f1;
    }
}

extern "C" void kernel_launch(void* const* d_in, const int* in_sizes, int n_in,
                              void* d_out, int out_size, void* d_ws, size_t ws_size,
                              hipStream_t stream)
{
    const float* x        = (const float*)d_in[0];
    const float* y        = (const float*)d_in[1];
    const float* w_fc2_t  = (const float*)d_in[12];
    const float* b_fc2_t  = (const float*)d_in[13];
    const float* w_fc2_v  = (const float*)d_in[14];
    const float* b_fc2_v  = (const float*)d_in[15];
    const float* wvec     = (const float*)d_in[18];

    unsigned short* wv_bf = (unsigned short*)d_ws;   // 262144 bf16
    unsigned short* wt_bf = wv_bf + 262144;          // 262144 bf16

    // 1) weights -> bf16
    cvt_k<<<dim3(256, 2), 256, 0, stream>>>(w_fc2_v, w_fc2_t, wv_bf, wt_bf);
    // 2) fused softpool + fc2 + residual + softmax + concat
    fused_k<<<dim3(M_ROWS/16, 2), 256, 0, stream>>>(
        x, y, wv_bf, wt_bf, b_fc2_v, b_fc2_t, wvec, (float*)d_out);
}

// Round 3
// 39.894 us; speedup vs baseline: 1.1076x; 1.1076x over previous
//
#include <hip/hip_runtime.h>
#include <hip/hip_bf16.h>

// Problem constants
#define M_ROWS   1792                 // 7 * 256 softpool rows
#define KDIM     512
#define OUT_FEAT_SZ (M_ROWS*1024)     // 1835008
#define OUT_HAT_SZ  (M_ROWS*512)      // 917504

typedef __attribute__((ext_vector_type(8))) __bf16 bf16x8;
typedef __attribute__((ext_vector_type(4))) float  f32x4;

__device__ __forceinline__ unsigned short f2bf(float f) {
    union { float f; unsigned int u; } v; v.f = f;
    unsigned int r = v.u + 0x7fffu + ((v.u >> 16) & 1u);   // RNE
    return (unsigned short)(r >> 16);
}

// f32 -> bf16 weight conversion (262144 elems each; blockIdx.y picks tensor)
__global__ __launch_bounds__(256) void cvt_k(
    const float* __restrict__ a, const float* __restrict__ b,
    unsigned short* __restrict__ oa, unsigned short* __restrict__ ob)
{
    const float* s = blockIdx.y ? b : a;
    unsigned short* d = blockIdx.y ? ob : oa;
    int i = blockIdx.x * 256 + threadIdx.x;   // 65536 threads, 4 elems each
    float4 v = reinterpret_cast<const float4*>(s)[i];
    ushort4 o; o.x=f2bf(v.x); o.y=f2bf(v.y); o.z=f2bf(v.z); o.w=f2bf(v.w);
    reinterpret_cast<ushort4*>(d)[i] = o;
}

// Fully fused: softpool3d (4,2,2)/(2,2,2) of the block's 16 output rows ->
// LDS {bf16 A-tile, f32 residual}, then C = A @ W^T + bias (+ residual for
// side 0), row-softmax over N=512, write hat + scaled feature half.
// Block = 16 rows x N=512, 1024 threads (16 waves) for latency hiding:
//   softpool: thread owns 1 d'-pair x 4 rows (4x shorter chains than 256-thr)
//   GEMM:     wave w owns cols [w*32, w*32+32) (2 MFMA accumulators)
//   softmax:  wave w owns row w
__global__ __launch_bounds__(1024) void fused_k(
    const float* __restrict__ x, const float* __restrict__ y,
    const unsigned short* __restrict__ wv_bf, const unsigned short* __restrict__ wt_bf,
    const float* __restrict__ b_v, const float* __restrict__ b_t,
    const float* __restrict__ wvec, float* __restrict__ d_out)
{
    const int side = blockIdx.y;
    const float* in          = side ? y     : x;
    const unsigned short* B  = side ? wt_bf : wv_bf;
    const float* bias        = side ? b_t   : b_v;
    const int mbase = blockIdx.x * 16;
    const int bp = mbase >> 8;       // b' (constant within tile: 256 % 16 == 0)
    const int l0 = mbase & 255;      // l' base

    __shared__ unsigned short tA[16 * 520];  // bf16 softpool tile (A), padded
    __shared__ float resl[16 * 516];         // f32 softpool (residual) -> logits

    const int tid = threadIdx.x;
    const int u  = tid & 255;        // d'-pair (d' = 2u, 2u+1)
    const int rg = tid >> 8;         // 0..3 row group

    // ---- softpool phase: 4 rows per thread
    #pragma unroll
    for (int ri = 0; ri < 4; ++ri) {
        int r = rg * 4 + ri;
        const float* base = in + ((size_t)(2*bp) * 512 + 2*(l0 + r)) * 1024 + 4*u;
        float num0=0.f, den0=0.f, num1=0.f, den1=0.f;
        #pragma unroll
        for (int i = 0; i < 4; ++i) {
            #pragma unroll
            for (int j = 0; j < 2; ++j) {
                float4 v = *reinterpret_cast<const float4*>(base + ((size_t)(i*512 + j))*1024);
                float e0=__expf(v.x), e1=__expf(v.y), e2=__expf(v.z), e3=__expf(v.w);
                num0 += e0*v.x + e1*v.y;  den0 += e0 + e1;
                num1 += e2*v.z + e3*v.w;  den1 += e2 + e3;
            }
        }
        float s0 = num0/den0, s1 = num1/den1;
        *reinterpret_cast<float2*>(&resl[r*516 + 2*u]) = make_float2(s0, s1);
        unsigned int pk = (unsigned int)f2bf(s0) | ((unsigned int)f2bf(s1) << 16);
        *reinterpret_cast<unsigned int*>(&tA[r*520 + 2*u]) = pk;
    }
    __syncthreads();

    // ---- GEMM phase: 16 waves, wave w -> cols [w*32, w*32+32)
    const int lane = tid & 63;
    const int w    = tid >> 6;       // 0..15
    const int arow = lane & 15;
    const int kq   = lane >> 4;      // 0..3
    const int nb   = w * 32;

    f32x4 acc0 = (f32x4){0.f,0.f,0.f,0.f};
    f32x4 acc1 = (f32x4){0.f,0.f,0.f,0.f};

    #pragma unroll
    for (int ks = 0; ks < 16; ++ks) {
        int kk = ks*32 + kq*8;
        bf16x8 af  = *reinterpret_cast<const bf16x8*>(&tA[arow*520 + kk]);
        bf16x8 bf0 = *reinterpret_cast<const bf16x8*>(B + (size_t)(nb      + arow) * KDIM + kk);
        bf16x8 bf1 = *reinterpret_cast<const bf16x8*>(B + (size_t)(nb + 16 + arow) * KDIM + kk);
        acc0 = __builtin_amdgcn_mfma_f32_16x16x32_bf16(af, bf0, acc0, 0, 0, 0);
        acc1 = __builtin_amdgcn_mfma_f32_16x16x32_bf16(af, bf1, acc1, 0, 0, 0);
    }

    // ---- epilogue: logits = acc + bias (+ residual, side 0), in-place in resl
    #pragma unroll
    for (int t = 0; t < 2; ++t) {
        int n = nb + t*16 + arow;
        float bn = bias[n];
        f32x4 a = t ? acc1 : acc0;
        #pragma unroll
        for (int i = 0; i < 4; ++i) {
            int row = kq*4 + i;    // C/D: col=lane&15, row=(lane>>4)*4+i
            float v = a[i] + bn;
            if (side == 0) v += resl[row*516 + n];
            resl[row*516 + n] = v;
        }
    }
    __syncthreads();

    // ---- softmax: wave w handles row w (full 512 cols, 8 per lane)
    float ew0 = __expf(wvec[0]), ew1 = __expf(wvec[1]);
    float wsc = (side ? ew1 : ew0) / (ew0 + ew1);
    float* feat = d_out;
    float* hat  = d_out + OUT_FEAT_SZ + (size_t)side * OUT_HAT_SZ;

    {
        int m = mbase + w;
        const float* lp = &resl[w*516 + lane*8];
        float4 v0 = *reinterpret_cast<const float4*>(lp);
        float4 v1 = *reinterpret_cast<const float4*>(lp + 4);
        float mx = fmaxf(fmaxf(fmaxf(v0.x,v0.y), fmaxf(v0.z,v0.w)),
                         fmaxf(fmaxf(v1.x,v1.y), fmaxf(v1.z,v1.w)));
        #pragma unroll
        for (int s = 32; s; s >>= 1) mx = fmaxf(mx, __shfl_xor(mx, s));
        float e0=__expf(v0.x-mx), e1=__expf(v0.y-mx), e2=__expf(v0.z-mx), e3=__expf(v0.w-mx);
        float e4=__expf(v1.x-mx), e5=__expf(v1.y-mx), e6=__expf(v1.z-mx), e7=__expf(v1.w-mx);
        float sum = ((e0+e1)+(e2+e3)) + ((e4+e5)+(e6+e7));
        #pragma unroll
        for (int s = 32; s; s >>= 1) sum += __shfl_xor(sum, s);
        float inv = 1.f / sum;
        float4 p0 = {e0*inv, e1*inv, e2*inv, e3*inv};
        float4 p1 = {e4*inv, e5*inv, e6*inv, e7*inv};
        *reinterpret_cast<float4*>(&hat[(size_t)m*512 + lane*8])     = p0;
        *reinterpret_cast<float4*>(&hat[(size_t)m*512 + lane*8 + 4]) = p1;
        float4 f0 = {p0.x*wsc, p0.y*wsc, p0.z*wsc, p0.w*wsc};
        float4 f1 = {p1.x*wsc, p1.y*wsc, p1.z*wsc, p1.w*wsc};
        size_t fo = (size_t)m*1024 + side*512 + lane*8;
        *reinterpret_cast<float4*>(&feat[fo])     = f0;
        *reinterpret_cast<float4*>(&feat[fo + 4]) = f1;
    }
}

extern "C" void kernel_launch(void* const* d_in, const int* in_sizes, int n_in,
                              void* d_out, int out_size, void* d_ws, size_t ws_size,
                              hipStream_t stream)
{
    const float* x        = (const float*)d_in[0];
    const float* y        = (const float*)d_in[1];
    const float* w_fc2_t  = (const float*)d_in[12];
    const float* b_fc2_t  = (const float*)d_in[13];
    const float* w_fc2_v  = (const float*)d_in[14];
    const float* b_fc2_v  = (const float*)d_in[15];
    const float* wvec     = (const float*)d_in[18];

    unsigned short* wv_bf = (unsigned short*)d_ws;   // 262144 bf16
    unsigned short* wt_bf = wv_bf + 262144;          // 262144 bf16

    // 1) weights -> bf16
    cvt_k<<<dim3(256, 2), 256, 0, stream>>>(w_fc2_v, w_fc2_t, wv_bf, wt_bf);
    // 2) fused softpool + fc2 + residual + softmax + concat (16 waves/block)
    fused_k<<<dim3(M_ROWS/16, 2), 1024, 0, stream>>>(
        x, y, wv_bf, wt_bf, b_fc2_v, b_fc2_t, wvec, (float*)d_out);
}